// Round 10
// baseline (2446.202 us; speedup 1.0000x reference)
//
#include <hip/hip_runtime.h>
#include <hip/hip_bf16.h>

#define TT 512
#define BB 64
#define II 256
#define HH 1024
#define NWG 256
#define MB 16          // batches per WG (4 batch groups)
#define NJ 16          // hidden units per WG (64 j-tiles)
#define NR 64          // packed gate rows per WG (16 j x 4 gates, p = j*4+g)
#define KTOT 1280      // packed weight row: 256 (x) + 1024 (h)
#define WU 120         // Wh k-units (16B) kept in LDS; units 120..127 in regs
#define WROWB 1920     // bytes per Wl row (120 units)
#define HROWB 2048     // bytes per Hs row (128 units, bf16)
#define HW32 65536     // u32 words per h buffer (B*H)
#define MAXTRY (1 << 20)

typedef __bf16 bf16x8 __attribute__((ext_vector_type(8)));
typedef float f32x4 __attribute__((ext_vector_type(4)));
typedef unsigned uint32x4 __attribute__((ext_vector_type(4)));
typedef unsigned uint32x2 __attribute__((ext_vector_type(2)));

__device__ inline uint32x4 ld16_sc1(const void* p) {
  uint32x4 r;
  asm volatile("global_load_dwordx4 %0, %1, off sc1" : "=&v"(r) : "v"(p));
  return r;
}

// issue this wave's staged region: rows [wq*4,+4) of tagged-u32 h buffer
__device__ inline void stage_issue(uint32x4 (&tmp)[16], const unsigned* __restrict__ hsrc,
                                   int b0, int wq, int lane) {
#pragma unroll
  for (int q = 0; q < 16; ++q) {
    int idx = q * 64 + lane;          // 0..1023
    int rl = wq * 4 + (idx >> 8);     // local batch row
    int uq = idx & 255;               // 16B unit (4 u32) within row
    tmp[q] = ld16_sc1(hsrc + (size_t)(b0 + rl) * HH + uq * 4);
  }
}

// ---------------- prep kernels ----------------

__global__ __launch_bounds__(256) void k_cast_inputs(const float* __restrict__ in,
                                                     __hip_bfloat16* __restrict__ outp) {
  int i = (blockIdx.x * 256 + threadIdx.x) * 4;
  float4 v = *reinterpret_cast<const float4*>(in + i);
  outp[i + 0] = __float2bfloat16(v.x);
  outp[i + 1] = __float2bfloat16(v.y);
  outp[i + 2] = __float2bfloat16(v.z);
  outp[i + 3] = __float2bfloat16(v.w);
}

// Packed row p = j*4 + gate (gate order i,f,g,o), cols [0:256)=Wx, [256:1280)=Wh
__global__ __launch_bounds__(256) void k_pack_w(
    const float* __restrict__ wxi, const float* __restrict__ whi,
    const float* __restrict__ wxf, const float* __restrict__ whf,
    const float* __restrict__ wxg, const float* __restrict__ whg,
    const float* __restrict__ wxo, const float* __restrict__ who,
    __hip_bfloat16* __restrict__ Wp) {
  int t = blockIdx.x * 256 + threadIdx.x;   // 0 .. 4096*320
  int p = t / 320;
  int k4 = (t - p * 320) * 4;
  int j = p >> 2, gate = p & 3;
  const float* wx = (gate == 0) ? wxi : (gate == 1) ? wxf : (gate == 2) ? wxg : wxo;
  const float* wh = (gate == 0) ? whi : (gate == 1) ? whf : (gate == 2) ? whg : who;
  float4 v;
  if (k4 < II) v = *reinterpret_cast<const float4*>(wx + (size_t)j * II + k4);
  else         v = *reinterpret_cast<const float4*>(wh + (size_t)j * HH + (k4 - II));
  __hip_bfloat16* o = Wp + (size_t)p * KTOT + k4;
  o[0] = __float2bfloat16(v.x);
  o[1] = __float2bfloat16(v.y);
  o[2] = __float2bfloat16(v.z);
  o[3] = __float2bfloat16(v.w);
}

__global__ __launch_bounds__(256) void k_pack_bias_h0(
    const float* __restrict__ bii, const float* __restrict__ bhi,
    const float* __restrict__ bif, const float* __restrict__ bhf,
    const float* __restrict__ bg,  const float* __restrict__ bhg,
    const float* __restrict__ bio, const float* __restrict__ bho,
    const float* __restrict__ h0, float* __restrict__ biasp,
    unsigned* __restrict__ hb) {
  int i = blockIdx.x * 256 + threadIdx.x;   // 0..65535
  if (i < 4096) {
    int j = i >> 2, gate = i & 3;
    const float* bi = (gate == 0) ? bii : (gate == 1) ? bif : (gate == 2) ? bg : bio;
    const float* bh = (gate == 0) ? bhi : (gate == 1) ? bhf : (gate == 2) ? bhg : bho;
    biasp[i] = bi[j] + bh[j];
  }
  __hip_bfloat16 v = __float2bfloat16(h0[i]);
  hb[i] = (unsigned)*reinterpret_cast<unsigned short*>(&v);  // tag 0 | h0 bits
  hb[HW32 + i] = 0u;                                         // buffer 1: stale tag 0
}

// ---------------- persistent recurrent kernel ----------------
// R8 tiling. Tagged h words (u32 = gen<<16 | bf16). No flags. Publish =
// fire-and-forget per-thread 4B sc1. Stage-poll = load region, check embedded
// tags, bounded retry. Two __syncthreads per step (S1: Hs reads drained,
// S2: Hs writes visible).

__global__ __launch_bounds__(256, 1) void k_lstm(
    const __hip_bfloat16* __restrict__ xb,
    const __hip_bfloat16* __restrict__ Wp,
    const float* __restrict__ biasp,
    const float* __restrict__ c0,
    unsigned* __restrict__ hbuf,          // 2 x (B,H) tagged u32 ping-pong
    float* __restrict__ out)
{
  extern __shared__ __align__(16) char smem[];
  char* Wl = smem;                        // 122880: Wh 64 rows x 120 units, XOR-swz
  char* Hs = smem + 122880;               // 32768: staged h, 16 rows x 128 units bf16
  char* Zx = smem + 155648;               // 5120: per-wave z exchange

  const int tid = threadIdx.x;
  const int lane = tid & 63;
  const int wq = tid >> 6;
  const int bt = blockIdx.x >> 6;        // batch group 0..3
  const int gt = blockIdx.x & 63;        // j tile 0..63
  const int b0 = bt * MB;
  const int r0 = gt * NR;

  const int l15 = lane & 15;
  const int kqu = lane >> 4;             // 0..3 (16B unit within 32-k chunk)

  // ---- prologue: stage Wh k-units 0..119 -> Wl ----
  {
    const int u = tid & 127;
    const bool act = u < WU;
    uint32x4 wtmp[16];
#pragma unroll
    for (int q = 0; q < 16; ++q) {
      int row = q * 2 + (tid >> 7);
      if (act) wtmp[q] = *reinterpret_cast<const uint32x4*>(
          Wp + (size_t)(r0 + row) * KTOT + II + u * 8);
    }
#pragma unroll
    for (int q = 0; q < 16; ++q) {
      int row = q * 2 + (tid >> 7);
      if (act) *reinterpret_cast<uint32x4*>(Wl + row * WROWB + ((u ^ (row & 7)) << 4)) = wtmp[q];
    }
#pragma unroll
    for (int q = 0; q < 16; ++q) {
      int row = 32 + q * 2 + (tid >> 7);
      if (act) wtmp[q] = *reinterpret_cast<const uint32x4*>(
          Wp + (size_t)(r0 + row) * KTOT + II + u * 8);
    }
#pragma unroll
    for (int q = 0; q < 16; ++q) {
      int row = 32 + q * 2 + (tid >> 7);
      if (act) *reinterpret_cast<uint32x4*>(Wl + row * WROWB + ((u ^ (row & 7)) << 4)) = wtmp[q];
    }
  }

  // ---- wave's weights in registers: Wx (8 frags) + Wh tail units 120..127 ----
  const int brow = r0 + wq * 16 + l15;
  bf16x8 wxr[8], wht0, wht1;
  {
    const __hip_bfloat16* ws = Wp + (size_t)brow * KTOT + kqu * 8;
#pragma unroll
    for (int kk = 0; kk < 8; ++kk)
      wxr[kk] = *reinterpret_cast<const bf16x8*>(ws + kk * 32);
    wht0 = *reinterpret_cast<const bf16x8*>(ws + II + 960);
    wht1 = *reinterpret_cast<const bf16x8*>(ws + II + 992);
  }

  // ---- epilogue cell identity ----
  const int m_e = 4 * kqu + (lane & 3);            // batch 0..15
  const int tq = (lane >> 2) & 3;                  // j offset within wave
  const int j_g = gt * NJ + wq * 4 + tq;
  const int b_g = b0 + m_e;
  const float4 bias = *reinterpret_cast<const float4*>(biasp + j_g * 4);
  float c_reg = c0[(size_t)b_g * HH + j_g];

  // ---- fragment geometry ----
  const int hs_swz = l15 & 7;
  const int bn_row = wq * 16 + l15;
  const int bn_swz = bn_row & 7;
  char* ZxW = Zx + wq * 1280;

  uint32x4 tmp[16];

  // ---- prologue: stage-poll h(0) (tag 0) and repack to Hs ----
  stage_issue(tmp, hbuf, b0, wq, lane);
  {
    int tries = 0;
    for (;;) {
      asm volatile("s_waitcnt vmcnt(0)" ::: "memory");
      __builtin_amdgcn_sched_barrier(0);
      unsigned bad = 0;
#pragma unroll
      for (int q = 0; q < 16; ++q) {
        bad |= (tmp[q].x >> 16); bad |= (tmp[q].y >> 16);
        bad |= (tmp[q].z >> 16); bad |= (tmp[q].w >> 16);
      }
      if (__all(bad == 0) || ++tries > MAXTRY) break;
      stage_issue(tmp, hbuf, b0, wq, lane);
    }
  }
#pragma unroll
  for (int q = 0; q < 16; ++q) {
    int idx = q * 64 + lane;
    int rl = wq * 4 + (idx >> 8);
    int uq = idx & 255;
    unsigned lo = (tmp[q].x & 0xFFFFu) | (tmp[q].y << 16);
    unsigned hi = (tmp[q].z & 0xFFFFu) | (tmp[q].w << 16);
    *reinterpret_cast<uint32x2*>(Hs + rl * HROWB + ((((uq >> 1) ^ (rl & 7)) << 4) + (uq & 1) * 8))
        = (uint32x2){lo, hi};
  }

  // ---- prologue: x-part MFMA for t=0 ----
  const __hip_bfloat16* xrowA = xb + (size_t)(b0 + l15) * (TT * II) + kqu * 8;
  f32x4 accs[4];
#pragma unroll
  for (int q = 0; q < 4; ++q) accs[q] = (f32x4){0.f, 0.f, 0.f, 0.f};
#pragma unroll
  for (int kk = 0; kk < 8; ++kk) {
    bf16x8 xa = *reinterpret_cast<const bf16x8*>(xrowA + kk * 32);
    accs[kk & 3] = __builtin_amdgcn_mfma_f32_16x16x32_bf16(xa, wxr[kk], accs[kk & 3], 0, 0, 0);
  }

  __syncthreads();

  for (int t = 0; t < TT; ++t) {
    // ---- A: h-part MFMA ----
#pragma unroll
    for (int kk = 0; kk < 30; ++kk) {
      int u = kk * 4 + kqu;
      bf16x8 a = *reinterpret_cast<const bf16x8*>(Hs + l15 * HROWB + ((u ^ hs_swz) << 4));
      bf16x8 b = *reinterpret_cast<const bf16x8*>(Wl + bn_row * WROWB + ((u ^ bn_swz) << 4));
      accs[kk & 3] = __builtin_amdgcn_mfma_f32_16x16x32_bf16(a, b, accs[kk & 3], 0, 0, 0);
    }
    {
      int u = 120 + kqu;
      bf16x8 a = *reinterpret_cast<const bf16x8*>(Hs + l15 * HROWB + ((u ^ hs_swz) << 4));
      accs[2] = __builtin_amdgcn_mfma_f32_16x16x32_bf16(a, wht0, accs[2], 0, 0, 0);
    }
    {
      int u = 124 + kqu;
      bf16x8 a = *reinterpret_cast<const bf16x8*>(Hs + l15 * HROWB + ((u ^ hs_swz) << 4));
      accs[3] = __builtin_amdgcn_mfma_f32_16x16x32_bf16(a, wht1, accs[3], 0, 0, 0);
    }
    f32x4 acc = (accs[0] + accs[1]) + (accs[2] + accs[3]);

    // ---- B: in-wave z exchange via LDS (drains this wave's Hs reads too) ----
    *reinterpret_cast<f32x4*>(ZxW + l15 * 80 + kqu * 16) = acc;
    asm volatile("s_waitcnt lgkmcnt(0)" ::: "memory");
    __builtin_amdgcn_sched_barrier(0);
    float zi = *reinterpret_cast<const float*>(ZxW + (4 * tq + 0) * 80 + m_e * 4) + bias.x;
    float zf = *reinterpret_cast<const float*>(ZxW + (4 * tq + 1) * 80 + m_e * 4) + bias.y;
    float zg = *reinterpret_cast<const float*>(ZxW + (4 * tq + 2) * 80 + m_e * 4) + bias.z;
    float zo = *reinterpret_cast<const float*>(ZxW + (4 * tq + 3) * 80 + m_e * 4) + bias.w;

    float ig = 1.f / (1.f + __expf(-zi));
    float fg = 1.f / (1.f + __expf(-zf));
    float gg = 2.f / (1.f + __expf(-2.f * zg)) - 1.f;
    float og = 1.f / (1.f + __expf(-zo));
    c_reg = fg * c_reg + ig * gg;
    float tc = 2.f / (1.f + __expf(-2.f * c_reg)) - 1.f;
    float h = og * tc;

    if (t == TT - 1) {
      out[(size_t)b_g * (TT * HH) + (size_t)t * HH + j_g] = h;
      out[(size_t)BB * TT * HH + (size_t)b_g * HH + j_g] = h;
      out[(size_t)BB * TT * HH + BB * HH + (size_t)b_g * HH + j_g] = c_reg;
      break;
    }

    // ---- C: publish tagged h word, fire-and-forget ----
    const int nxt = (t + 1) & 1;
    const unsigned gen = (unsigned)(t + 1);
    {
      __hip_bfloat16 hb16 = __float2bfloat16(h);
      unsigned pub = (gen << 16) | (unsigned)*reinterpret_cast<unsigned short*>(&hb16);
      unsigned* dst = hbuf + (size_t)nxt * HW32 + (size_t)b_g * HH + j_g;
      asm volatile("global_store_dword %0, %1, off sc1" :: "v"(dst), "v"(pub) : "memory");
    }

    // ---- D: out store + x(t+1)-part MFMA + issue next stage loads ----
    out[(size_t)b_g * (TT * HH) + (size_t)t * HH + j_g] = h;
#pragma unroll
    for (int q = 0; q < 4; ++q) accs[q] = (f32x4){0.f, 0.f, 0.f, 0.f};
    {
      const __hip_bfloat16* xp = xrowA + (size_t)(t + 1) * II;
#pragma unroll
      for (int kk = 0; kk < 8; ++kk) {
        bf16x8 xa = *reinterpret_cast<const bf16x8*>(xp + kk * 32);
        accs[kk & 3] = __builtin_amdgcn_mfma_f32_16x16x32_bf16(xa, wxr[kk], accs[kk & 3], 0, 0, 0);
      }
    }
    const unsigned* hsrc = hbuf + (size_t)nxt * HW32;
    stage_issue(tmp, hsrc, b0, wq, lane);

    __syncthreads();                     // S1: all waves' Hs reads drained

    // ---- E: tag-check poll + repack to Hs ----
    {
      int tries = 0;
      for (;;) {
        asm volatile("s_waitcnt vmcnt(0)" ::: "memory");   // also drains publish stores
        __builtin_amdgcn_sched_barrier(0);
        unsigned bad = 0;
#pragma unroll
        for (int q = 0; q < 16; ++q) {
          bad |= (tmp[q].x >> 16) ^ gen; bad |= (tmp[q].y >> 16) ^ gen;
          bad |= (tmp[q].z >> 16) ^ gen; bad |= (tmp[q].w >> 16) ^ gen;
        }
        if (__all(bad == 0) || ++tries > MAXTRY) break;
        stage_issue(tmp, hsrc, b0, wq, lane);
      }
    }
#pragma unroll
    for (int q = 0; q < 16; ++q) {
      int idx = q * 64 + lane;
      int rl = wq * 4 + (idx >> 8);
      int uq = idx & 255;
      unsigned lo = (tmp[q].x & 0xFFFFu) | (tmp[q].y << 16);
      unsigned hi = (tmp[q].z & 0xFFFFu) | (tmp[q].w << 16);
      *reinterpret_cast<uint32x2*>(Hs + rl * HROWB + ((((uq >> 1) ^ (rl & 7)) << 4) + (uq & 1) * 8))
          = (uint32x2){lo, hi};
    }
    __syncthreads();                     // S2: Hs writes visible to all waves
  }
}

// ---------------- launcher ----------------

extern "C" void kernel_launch(void* const* d_in, const int* in_sizes, int n_in,
                              void* d_out, int out_size, void* d_ws, size_t ws_size,
                              hipStream_t stream) {
  (void)in_sizes; (void)n_in; (void)out_size; (void)ws_size;
  const float* inputs = (const float*)d_in[0];
  const float* h0 = (const float*)d_in[1];
  const float* c0 = (const float*)d_in[2];
  const float* w_ii = (const float*)d_in[3];
  const float* w_hi = (const float*)d_in[4];
  const float* b_ii = (const float*)d_in[5];
  const float* b_hi = (const float*)d_in[6];
  const float* w_if = (const float*)d_in[7];
  const float* w_hf = (const float*)d_in[8];
  const float* b_if = (const float*)d_in[9];
  const float* b_hf = (const float*)d_in[10];
  const float* w_io = (const float*)d_in[11];
  const float* w_ho = (const float*)d_in[12];
  const float* b_io = (const float*)d_in[13];
  const float* b_ho = (const float*)d_in[14];
  const float* w_ig = (const float*)d_in[15];
  const float* w_hg = (const float*)d_in[16];
  const float* b_ig = (const float*)d_in[17];
  const float* b_hg = (const float*)d_in[18];

  char* ws = (char*)d_ws;
  __hip_bfloat16* xb    = (__hip_bfloat16*)ws;                    // 16,777,216 B
  __hip_bfloat16* Wp    = (__hip_bfloat16*)(ws + 16777216);       // 10,485,760 B
  float*          biasp = (float*)(ws + 27262976);                // 16,384 B
  unsigned*       hbuf  = (unsigned*)(ws + 27279360);             // 524,288 B (tagged u32 x2)
  float* out = (float*)d_out;

  k_cast_inputs<<<8192, 256, 0, stream>>>(inputs, xb);
  k_pack_w<<<5120, 256, 0, stream>>>(w_ii, w_hi, w_if, w_hf, w_ig, w_hg, w_io, w_ho, Wp);
  k_pack_bias_h0<<<256, 256, 0, stream>>>(b_ii, b_hi, b_if, b_hf, b_ig, b_hg,
                                          b_io, b_ho, h0, biasp, hbuf);

  const int lds_bytes = 160768;
  hipFuncSetAttribute((const void*)k_lstm,
                      hipFuncAttributeMaxDynamicSharedMemorySize, lds_bytes);
  void* args[] = {(void*)&xb, (void*)&Wp, (void*)&biasp, (void*)&c0,
                  (void*)&hbuf, (void*)&out};
  hipError_t e = hipLaunchCooperativeKernel((void*)k_lstm, dim3(NWG), dim3(256),
                                            args, lds_bytes, stream);
  if (e != hipSuccess) {
    // Fallback: plain launch. 256 WGs at 1 WG/CU (LDS-bound) on 256 CUs are
    // de-facto co-resident; the barrier protocol is flag/tag-based only.
    k_lstm<<<dim3(NWG), dim3(256), lds_bytes, stream>>>(xb, Wp, biasp, c0, hbuf, out);
  }
}

// Round 11
// 2280.644 us; speedup vs baseline: 1.0726x; 1.0726x over previous
//
#include <hip/hip_runtime.h>
#include <hip/hip_bf16.h>

#define TT 512
#define BB 64
#define II 256
#define HH 1024
#define NWG 256
#define MB 16          // batches per WG (4 batch groups)
#define NJ 16          // hidden units per WG (64 j-tiles)
#define NR 64          // packed gate rows per WG (16 j x 4 gates, p = j*4+g)
#define KTOT 1280      // packed weight row: 256 (x) + 1024 (h)
#define WU 120         // Wh k-units (16B) kept in LDS; units 120..127 in regs
#define WROWB 1920     // bytes per Wl row (120 units)
#define HROWB 2048     // bytes per Hs row (128 units, bf16)
#define FPAD 16        // dwords per flag slot (64B padding -> spread MALL slices)
#define MAXTRY (1 << 20)

typedef __bf16 bf16x8 __attribute__((ext_vector_type(8)));
typedef float f32x4 __attribute__((ext_vector_type(4)));
typedef unsigned uint32x4 __attribute__((ext_vector_type(4)));
typedef unsigned uint32x2 __attribute__((ext_vector_type(2)));

__device__ inline uint32x4 ld16_sc1(const void* p) {
  uint32x4 r;
  asm volatile("global_load_dwordx4 %0, %1, off sc1" : "=&v"(r) : "v"(p));
  return r;
}

// ---------------- prep kernels ----------------

__global__ __launch_bounds__(256) void k_cast_inputs(const float* __restrict__ in,
                                                     __hip_bfloat16* __restrict__ outp) {
  int i = (blockIdx.x * 256 + threadIdx.x) * 4;
  float4 v = *reinterpret_cast<const float4*>(in + i);
  outp[i + 0] = __float2bfloat16(v.x);
  outp[i + 1] = __float2bfloat16(v.y);
  outp[i + 2] = __float2bfloat16(v.z);
  outp[i + 3] = __float2bfloat16(v.w);
}

// Packed row p = j*4 + gate (gate order i,f,g,o), cols [0:256)=Wx, [256:1280)=Wh
__global__ __launch_bounds__(256) void k_pack_w(
    const float* __restrict__ wxi, const float* __restrict__ whi,
    const float* __restrict__ wxf, const float* __restrict__ whf,
    const float* __restrict__ wxg, const float* __restrict__ whg,
    const float* __restrict__ wxo, const float* __restrict__ who,
    __hip_bfloat16* __restrict__ Wp) {
  int t = blockIdx.x * 256 + threadIdx.x;   // 0 .. 4096*320
  int p = t / 320;
  int k4 = (t - p * 320) * 4;
  int j = p >> 2, gate = p & 3;
  const float* wx = (gate == 0) ? wxi : (gate == 1) ? wxf : (gate == 2) ? wxg : wxo;
  const float* wh = (gate == 0) ? whi : (gate == 1) ? whf : (gate == 2) ? whg : who;
  float4 v;
  if (k4 < II) v = *reinterpret_cast<const float4*>(wx + (size_t)j * II + k4);
  else         v = *reinterpret_cast<const float4*>(wh + (size_t)j * HH + (k4 - II));
  __hip_bfloat16* o = Wp + (size_t)p * KTOT + k4;
  o[0] = __float2bfloat16(v.x);
  o[1] = __float2bfloat16(v.y);
  o[2] = __float2bfloat16(v.z);
  o[3] = __float2bfloat16(v.w);
}

__global__ __launch_bounds__(256) void k_pack_bias_h0(
    const float* __restrict__ bii, const float* __restrict__ bhi,
    const float* __restrict__ bif, const float* __restrict__ bhf,
    const float* __restrict__ bg,  const float* __restrict__ bhg,
    const float* __restrict__ bio, const float* __restrict__ bho,
    const float* __restrict__ h0, float* __restrict__ biasp,
    __hip_bfloat16* __restrict__ hb, unsigned* __restrict__ flags) {
  int i = blockIdx.x * 256 + threadIdx.x;   // 0..65535
  if (i < 4096) {
    int j = i >> 2, gate = i & 3;
    const float* bi = (gate == 0) ? bii : (gate == 1) ? bif : (gate == 2) ? bg : bio;
    const float* bh = (gate == 0) ? bhi : (gate == 1) ? bhf : (gate == 2) ? bhg : bho;
    biasp[i] = bi[j] + bh[j];
    flags[i] = 0;    // 4 groups x 64 WG-flags x 16 padded dwords = 4096
  }
  hb[i] = __float2bfloat16(h0[i]);
}

// ---------------- persistent recurrent kernel ----------------
// R8 tiling/protocol (proven, 2181us). ONE delta: flag decongestion.
//  - per-WG flag (not per-wave), stored by tid0 AFTER an intra-WG sync (S0);
//    the sync certifies all 4 waves' publishes acked AND Hs reads drained,
//    so the W-after-R invariant R8 got from per-wave flags is preserved.
//  - flags padded to 64B each (group spans 16 MALL granules, not 4).
//  - only wave 0 polls (1 dword per lane, 64 lines); S1 releases siblings.

__global__ __launch_bounds__(256, 1) void k_lstm(
    const __hip_bfloat16* __restrict__ xb,
    const __hip_bfloat16* __restrict__ Wp,
    const float* __restrict__ biasp,
    const float* __restrict__ c0,
    __hip_bfloat16* __restrict__ hbuf,    // 2 x (B,H) bf16 ping-pong
    unsigned* __restrict__ flags,         // 4 groups x 64 x FPAD dwords
    float* __restrict__ out)
{
  extern __shared__ __align__(16) char smem[];
  char* Wl = smem;                        // 122880: Wh 64 rows x 120 units, XOR-swz
  char* Hs = smem + 122880;               // 32768: staged h, 16 rows x 128 units bf16
  char* Zx = smem + 155648;               // 5120: per-wave z exchange
  char* Ho = smem + 160768;               // 512: per-wave h bounce (4 x 128B)

  const int tid = threadIdx.x;
  const int lane = tid & 63;
  const int wq = tid >> 6;
  const int bt = blockIdx.x >> 6;        // batch group 0..3
  const int gt = blockIdx.x & 63;        // j tile 0..63
  const int b0 = bt * MB;
  const int r0 = gt * NR;

  const int l15 = lane & 15;
  const int kqu = lane >> 4;             // 0..3 (16B unit within 32-k chunk)

  // ---- prologue: stage Wh k-units 0..119 -> Wl ----
  {
    const int u = tid & 127;
    const bool act = u < WU;
    uint32x4 wtmp[16];
#pragma unroll
    for (int q = 0; q < 16; ++q) {
      int row = q * 2 + (tid >> 7);
      if (act) wtmp[q] = *reinterpret_cast<const uint32x4*>(
          Wp + (size_t)(r0 + row) * KTOT + II + u * 8);
    }
#pragma unroll
    for (int q = 0; q < 16; ++q) {
      int row = q * 2 + (tid >> 7);
      if (act) *reinterpret_cast<uint32x4*>(Wl + row * WROWB + ((u ^ (row & 7)) << 4)) = wtmp[q];
    }
#pragma unroll
    for (int q = 0; q < 16; ++q) {
      int row = 32 + q * 2 + (tid >> 7);
      if (act) wtmp[q] = *reinterpret_cast<const uint32x4*>(
          Wp + (size_t)(r0 + row) * KTOT + II + u * 8);
    }
#pragma unroll
    for (int q = 0; q < 16; ++q) {
      int row = 32 + q * 2 + (tid >> 7);
      if (act) *reinterpret_cast<uint32x4*>(Wl + row * WROWB + ((u ^ (row & 7)) << 4)) = wtmp[q];
    }
  }

  // ---- wave's weights in registers: Wx (8 frags) + Wh tail units 120..127 ----
  const int brow = r0 + wq * 16 + l15;
  bf16x8 wxr[8], wht0, wht1;
  {
    const __hip_bfloat16* ws = Wp + (size_t)brow * KTOT + kqu * 8;
#pragma unroll
    for (int kk = 0; kk < 8; ++kk)
      wxr[kk] = *reinterpret_cast<const bf16x8*>(ws + kk * 32);
    wht0 = *reinterpret_cast<const bf16x8*>(ws + II + 960);
    wht1 = *reinterpret_cast<const bf16x8*>(ws + II + 992);
  }

  // ---- epilogue cell identity ----
  const int m_e = 4 * kqu + (lane & 3);            // batch 0..15
  const int tq = (lane >> 2) & 3;                  // j offset within wave
  const int j_g = gt * NJ + wq * 4 + tq;
  const int b_g = b0 + m_e;
  const float4 bias = *reinterpret_cast<const float4*>(biasp + j_g * 4);
  float c_reg = c0[(size_t)b_g * HH + j_g];

  // ---- fragment geometry ----
  const int hs_swz = l15 & 7;
  const int bn_row = wq * 16 + l15;
  const int bn_swz = bn_row & 7;
  char* ZxW = Zx + wq * 1280;
  char* HoW = Ho + wq * 128;

  // ---- prologue: per-wave stage h(0) rows [wq*4,+4), coalesced sc1 ----
  {
    uint32x4 tmp[8];
#pragma unroll
    for (int q = 0; q < 8; ++q) {
      int idx = q * 64 + lane;                     // 0..511
      int rl = wq * 4 + (idx >> 7);
      int u = idx & 127;
      tmp[q] = ld16_sc1(hbuf + (size_t)(b0 + rl) * HH + u * 8);
    }
    asm volatile("s_waitcnt vmcnt(0)" ::: "memory");
    __builtin_amdgcn_sched_barrier(0);
#pragma unroll
    for (int q = 0; q < 8; ++q) {
      int idx = q * 64 + lane;
      int rl = wq * 4 + (idx >> 7);
      int u = idx & 127;
      *reinterpret_cast<uint32x4*>(Hs + rl * HROWB + ((u ^ (rl & 7)) << 4)) = tmp[q];
    }
  }

  // ---- prologue: x-part MFMA for t=0 ----
  const __hip_bfloat16* xrowA = xb + (size_t)(b0 + l15) * (TT * II) + kqu * 8;
  f32x4 accs[4];
#pragma unroll
  for (int q = 0; q < 4; ++q) accs[q] = (f32x4){0.f, 0.f, 0.f, 0.f};
#pragma unroll
  for (int kk = 0; kk < 8; ++kk) {
    bf16x8 xa = *reinterpret_cast<const bf16x8*>(xrowA + kk * 32);
    accs[kk & 3] = __builtin_amdgcn_mfma_f32_16x16x32_bf16(xa, wxr[kk], accs[kk & 3], 0, 0, 0);
  }

  __syncthreads();

  for (int t = 0; t < TT; ++t) {
    // ---- A: h-part MFMA (x-part already in accs) ----
#pragma unroll
    for (int kk = 0; kk < 30; ++kk) {
      int u = kk * 4 + kqu;
      bf16x8 a = *reinterpret_cast<const bf16x8*>(Hs + l15 * HROWB + ((u ^ hs_swz) << 4));
      bf16x8 b = *reinterpret_cast<const bf16x8*>(Wl + bn_row * WROWB + ((u ^ bn_swz) << 4));
      accs[kk & 3] = __builtin_amdgcn_mfma_f32_16x16x32_bf16(a, b, accs[kk & 3], 0, 0, 0);
    }
    {
      int u = 120 + kqu;
      bf16x8 a = *reinterpret_cast<const bf16x8*>(Hs + l15 * HROWB + ((u ^ hs_swz) << 4));
      accs[2] = __builtin_amdgcn_mfma_f32_16x16x32_bf16(a, wht0, accs[2], 0, 0, 0);
    }
    {
      int u = 124 + kqu;
      bf16x8 a = *reinterpret_cast<const bf16x8*>(Hs + l15 * HROWB + ((u ^ hs_swz) << 4));
      accs[3] = __builtin_amdgcn_mfma_f32_16x16x32_bf16(a, wht1, accs[3], 0, 0, 0);
    }
    f32x4 acc = (accs[0] + accs[1]) + (accs[2] + accs[3]);

    // ---- B: in-wave z exchange via LDS (drains this wave's Hs reads too) ----
    *reinterpret_cast<f32x4*>(ZxW + l15 * 80 + kqu * 16) = acc;
    asm volatile("s_waitcnt lgkmcnt(0)" ::: "memory");
    __builtin_amdgcn_sched_barrier(0);
    float zi = *reinterpret_cast<const float*>(ZxW + (4 * tq + 0) * 80 + m_e * 4) + bias.x;
    float zf = *reinterpret_cast<const float*>(ZxW + (4 * tq + 1) * 80 + m_e * 4) + bias.y;
    float zg = *reinterpret_cast<const float*>(ZxW + (4 * tq + 2) * 80 + m_e * 4) + bias.z;
    float zo = *reinterpret_cast<const float*>(ZxW + (4 * tq + 3) * 80 + m_e * 4) + bias.w;

    float ig = 1.f / (1.f + __expf(-zi));
    float fg = 1.f / (1.f + __expf(-zf));
    float gg = 2.f / (1.f + __expf(-2.f * zg)) - 1.f;
    float og = 1.f / (1.f + __expf(-zo));
    c_reg = fg * c_reg + ig * gg;
    float tc = 2.f / (1.f + __expf(-2.f * c_reg)) - 1.f;
    float h = og * tc;

    if (t == TT - 1) {
      out[(size_t)b_g * (TT * HH) + (size_t)t * HH + j_g] = h;
      out[(size_t)BB * TT * HH + (size_t)b_g * HH + j_g] = h;
      out[(size_t)BB * TT * HH + BB * HH + (size_t)b_g * HH + j_g] = c_reg;
      break;
    }

    // ---- C: h -> wave-local Ho bounce, publish 8B sc1, ack ----
    __hip_bfloat16 hb16 = __float2bfloat16(h);
    *reinterpret_cast<unsigned short*>(HoW + m_e * 8 + tq * 2) =
        *reinterpret_cast<unsigned short*>(&hb16);
    asm volatile("s_waitcnt lgkmcnt(0)" ::: "memory");
    __builtin_amdgcn_sched_barrier(0);

    const int nxt = (t + 1) & 1;
    const unsigned gen = (unsigned)(t + 1);
    if (lane < 16) {
      uint32x2 hv = *reinterpret_cast<const uint32x2*>(HoW + lane * 8);
      __hip_bfloat16* dst = hbuf + (size_t)nxt * (BB * HH)
                          + (size_t)(b0 + lane) * HH + gt * NJ + wq * 4;
      asm volatile("global_store_dwordx2 %0, %1, off sc1" :: "v"(dst), "v"(hv) : "memory");
    }
    asm volatile("s_waitcnt vmcnt(0)" ::: "memory");

    __syncthreads();                     // S0: all 4 waves' publishes acked

    // ---- WG flag (padded 64B slot), stored once per WG ----
    if (tid == 0) {
      asm volatile("global_store_dword %0, %1, off sc1"
                   :: "v"(flags + (bt * 64 + gt) * FPAD), "v"(gen) : "memory");
    }

    // ---- D: poll-window work: out store + x(t+1)-part MFMA ----
    out[(size_t)b_g * (TT * HH) + (size_t)t * HH + j_g] = h;
#pragma unroll
    for (int q = 0; q < 4; ++q) accs[q] = (f32x4){0.f, 0.f, 0.f, 0.f};
    {
      const __hip_bfloat16* xp = xrowA + (size_t)(t + 1) * II;
#pragma unroll
      for (int kk = 0; kk < 8; ++kk) {
        bf16x8 xa = *reinterpret_cast<const bf16x8*>(xp + kk * 32);
        accs[kk & 3] = __builtin_amdgcn_mfma_f32_16x16x32_bf16(xa, wxr[kk], accs[kk & 3], 0, 0, 0);
      }
    }

    // ---- E: wave 0 polls the group's 64 WG-flags (1 dword per lane) ----
    if (wq == 0) {
      const unsigned* fp = flags + (bt * 64 + lane) * FPAD;
      int tries = 0;
      unsigned f;
      for (;;) {
        asm volatile("global_load_dword %0, %1, off sc1\n\ts_waitcnt vmcnt(0)"
                     : "=&v"(f) : "v"(fp) : "memory");
        if (__all(f >= gen) || ++tries > MAXTRY) break;
      }
    }
    __syncthreads();                     // S1: release siblings (poll done)

    // ---- F: per-wave stage h(t+1) rows [wq*4,+4), coalesced sc1 ----
    {
      uint32x4 tmp[8];
      const __hip_bfloat16* hsrc = hbuf + (size_t)nxt * (BB * HH);
#pragma unroll
      for (int q = 0; q < 8; ++q) {
        int idx = q * 64 + lane;
        int rl = wq * 4 + (idx >> 7);
        int u = idx & 127;
        tmp[q] = ld16_sc1(hsrc + (size_t)(b0 + rl) * HH + u * 8);
      }
      asm volatile("s_waitcnt vmcnt(0)" ::: "memory");
      __builtin_amdgcn_sched_barrier(0);
#pragma unroll
      for (int q = 0; q < 8; ++q) {
        int idx = q * 64 + lane;
        int rl = wq * 4 + (idx >> 7);
        int u = idx & 127;
        *reinterpret_cast<uint32x4*>(Hs + rl * HROWB + ((u ^ (rl & 7)) << 4)) = tmp[q];
      }
    }
    __syncthreads();                     // S2: stage -> fragment-read handoff
  }
}

// ---------------- launcher ----------------

extern "C" void kernel_launch(void* const* d_in, const int* in_sizes, int n_in,
                              void* d_out, int out_size, void* d_ws, size_t ws_size,
                              hipStream_t stream) {
  (void)in_sizes; (void)n_in; (void)out_size; (void)ws_size;
  const float* inputs = (const float*)d_in[0];
  const float* h0 = (const float*)d_in[1];
  const float* c0 = (const float*)d_in[2];
  const float* w_ii = (const float*)d_in[3];
  const float* w_hi = (const float*)d_in[4];
  const float* b_ii = (const float*)d_in[5];
  const float* b_hi = (const float*)d_in[6];
  const float* w_if = (const float*)d_in[7];
  const float* w_hf = (const float*)d_in[8];
  const float* b_if = (const float*)d_in[9];
  const float* b_hf = (const float*)d_in[10];
  const float* w_io = (const float*)d_in[11];
  const float* w_ho = (const float*)d_in[12];
  const float* b_io = (const float*)d_in[13];
  const float* b_ho = (const float*)d_in[14];
  const float* w_ig = (const float*)d_in[15];
  const float* w_hg = (const float*)d_in[16];
  const float* b_ig = (const float*)d_in[17];
  const float* b_hg = (const float*)d_in[18];

  char* ws = (char*)d_ws;
  __hip_bfloat16* xb    = (__hip_bfloat16*)ws;                    // 16,777,216 B
  __hip_bfloat16* Wp    = (__hip_bfloat16*)(ws + 16777216);       // 10,485,760 B
  float*          biasp = (float*)(ws + 27262976);                // 16,384 B
  __hip_bfloat16* hbuf  = (__hip_bfloat16*)(ws + 27279360);       // 262,144 B
  unsigned*       flags = (unsigned*)(ws + 27541504);             // 16,384 B (padded)
  float* out = (float*)d_out;

  k_cast_inputs<<<8192, 256, 0, stream>>>(inputs, xb);
  k_pack_w<<<5120, 256, 0, stream>>>(w_ii, w_hi, w_if, w_hf, w_ig, w_hg, w_io, w_ho, Wp);
  k_pack_bias_h0<<<256, 256, 0, stream>>>(b_ii, b_hi, b_if, b_hf, b_ig, b_hg,
                                          b_io, b_ho, h0, biasp, hbuf, flags);

  const int lds_bytes = 161280;
  hipFuncSetAttribute((const void*)k_lstm,
                      hipFuncAttributeMaxDynamicSharedMemorySize, lds_bytes);
  void* args[] = {(void*)&xb, (void*)&Wp, (void*)&biasp, (void*)&c0,
                  (void*)&hbuf, (void*)&flags, (void*)&out};
  hipError_t e = hipLaunchCooperativeKernel((void*)k_lstm, dim3(NWG), dim3(256),
                                            args, lds_bytes, stream);
  if (e != hipSuccess) {
    // Fallback: plain launch. 256 WGs at 1 WG/CU (LDS-bound) on 256 CUs are
    // de-facto co-resident; the barrier protocol is flag-based only.
    k_lstm<<<dim3(NWG), dim3(256), lds_bytes, stream>>>(xb, Wp, biasp, c0, hbuf, flags, out);
  }
}